// Round 5
// baseline (121.974 us; speedup 1.0000x reference)
//
#include <hip/hip_runtime.h>
#include <hip/hip_fp16.h>

typedef float f32x2 __attribute__((ext_vector_type(2)));

#define NA    128   // batches
#define NPTS  256   // points per path
#define DD    16    // feature dim
#define MMI   255   // increments per axis (NPTS-1)
#define NSTEP 318   // MMI + 63 (wavefront steps)
#define GROWS 318   // skewed rows per problem (srow = rr + lane, rr in [0,255), lane in [0,64))
// G layout (fp16): G[prob][srow][col], srow in [0,318), col in [0,256).
// Cell (srow s, col 4l+k) holds g[rr = s - l][4l+k]; zero where rr outside [0, 255).
#define G_ELEMS ((size_t)3 * NA * GROWS * 256)
#define G_BYTES (G_ELEMS * 2)   // 62,521,344

__device__ __forceinline__ float wave_shr1(float x, float boundary) {
    int r = __builtin_amdgcn_update_dpp(
        __builtin_bit_cast(int, boundary),
        __builtin_bit_cast(int, x),
        0x138 /* wave_shr:1 */, 0xF, 0xF, false);
    return __builtin_bit_cast(float, r);
}

// ---------------- kernel 1: Gram increments, skewed fp16 ----------------
// grid 384*4 blocks x 256 threads. Block (prob, chunk) computes srows
// [80*chunk, min(80*chunk+80, 318)) of its problem. Thread owns col = tid.
__global__ __launch_bounds__(256)
void sig_gram(const float* __restrict__ X, const float* __restrict__ Y,
              __half* __restrict__ G) {
    const int bx    = blockIdx.x;
    const int pb    = bx >> 2;
    const int chunk = bx & 3;
    const int pair  = pb >> 7;     // 0: XX, 1: YY, 2: XY
    const int a     = pb & 127;
    const float* U = (pair == 1) ? Y : X;   // rows
    const float* V = (pair == 0) ? X : Y;   // cols
    U += (size_t)a * (NPTS * DD);
    V += (size_t)a * (NPTS * DD);

    __shared__ float dU[4][256][4];
    __shared__ float dV[4][256][4];

    const int tid = threadIdx.x;

    // stage dU, dV (row 255 zeroed)
    const float4* U4 = (const float4*)U;
    const float4* V4 = (const float4*)V;
    #pragma unroll
    for (int q = 0; q < 4; ++q) {
        float4 uval = make_float4(0.f, 0.f, 0.f, 0.f);
        float4 vval = make_float4(0.f, 0.f, 0.f, 0.f);
        if (tid < MMI) {
            float4 lo = U4[tid * 4 + q], hi = U4[tid * 4 + 4 + q];
            uval = make_float4(hi.x - lo.x, hi.y - lo.y, hi.z - lo.z, hi.w - lo.w);
            lo = V4[tid * 4 + q]; hi = V4[tid * 4 + 4 + q];
            vval = make_float4(hi.x - lo.x, hi.y - lo.y, hi.z - lo.z, hi.w - lo.w);
        }
        *(float4*)(&dU[q][tid][0]) = uval;
        *(float4*)(&dV[q][tid][0]) = vval;
    }
    __syncthreads();

    // own column vector in registers
    f32x2 v[8];
    #pragma unroll
    for (int q = 0; q < 4; ++q) {
        float4 t = *(const float4*)(&dV[q][tid][0]);
        v[2 * q + 0] = f32x2{t.x, t.y};
        v[2 * q + 1] = f32x2{t.z, t.w};
    }

    const int s0beg = 80 * chunk;
    const int s0end = (s0beg + 80 < GROWS) ? s0beg + 80 : GROWS;
    int rr = s0beg - (tid >> 2);                 // row for this col at srow s0
    __half* gp = G + (size_t)pb * (GROWS * 256) + (size_t)s0beg * 256 + tid;

    for (int s0 = s0beg; s0 < s0end; ++s0) {
        int rc = rr < 0 ? 0 : (rr > 255 ? 255 : rr);   // row 255 is zero
        f32x2 acc;
        {
            float4 t0 = *(const float4*)(&dU[0][rc][0]);
            float4 t1 = *(const float4*)(&dU[1][rc][0]);
            float4 t2 = *(const float4*)(&dU[2][rc][0]);
            float4 t3 = *(const float4*)(&dU[3][rc][0]);
            acc = f32x2{t0.x, t0.y} * v[0];
            acc = __builtin_elementwise_fma(f32x2{t0.z, t0.w}, v[1], acc);
            acc = __builtin_elementwise_fma(f32x2{t1.x, t1.y}, v[2], acc);
            acc = __builtin_elementwise_fma(f32x2{t1.z, t1.w}, v[3], acc);
            acc = __builtin_elementwise_fma(f32x2{t2.x, t2.y}, v[4], acc);
            acc = __builtin_elementwise_fma(f32x2{t2.z, t2.w}, v[5], acc);
            acc = __builtin_elementwise_fma(f32x2{t3.x, t3.y}, v[6], acc);
            acc = __builtin_elementwise_fma(f32x2{t3.z, t3.w}, v[7], acc);
        }
        float g = acc.x + acc.y;
        g = (rr < 0) ? 0.f : g;                 // low-side zero (high side via row 255)
        *gp = __float2half(g);
        gp += 256;
        ++rr;
    }
}

// ---------------- kernel 2: slim PDE wave over precomputed g ----------------
// One wave per (pair, batch). Lane l owns cols 4l..4l+3; step s reads the
// contiguous 512B skew-row s. Zero g => c1=c2=1 identity handles all bounds.
__global__ __launch_bounds__(64)
void sig_pde2(const __half* __restrict__ G, float* __restrict__ out) {
    const int pid  = blockIdx.x;
    const int pair = pid >> 7;
    const float w  = (pair == 2) ? (-2.0f / (float)NA) : (1.0f / (float)NA);
    const int lane = threadIdx.x;

    const __half* gp = G + (size_t)pid * (GROWS * 256) + 4 * lane;

    float kup0 = 1.f, kup1 = 1.f, kup2 = 1.f, kup3 = 1.f;
    float shnew = 1.f, shprev = 1.f;

    auto LOADK = [&](int k) { return *(const uint2*)(gp + k * 256); };

    auto STEP = [&](uint2 b) {
        float2 f01 = __half22float2(__builtin_bit_cast(__half2, b.x));
        float2 f23 = __half22float2(__builtin_bit_cast(__half2, b.y));
        f32x2 g01 = f32x2{f01.x, f01.y}, g23 = f32x2{f23.x, f23.y};
        f32x2 e01 = (g01 * g01) * f32x2{1.f / 12.f, 1.f / 12.f};
        f32x2 e23 = (g23 * g23) * f32x2{1.f / 12.f, 1.f / 12.f};
        f32x2 c1a = __builtin_elementwise_fma(g01, f32x2{0.5f, 0.5f},
                                              f32x2{1.f, 1.f}) + e01;
        f32x2 c1b = __builtin_elementwise_fma(g23, f32x2{0.5f, 0.5f},
                                              f32x2{1.f, 1.f}) + e23;
        f32x2 c2a = f32x2{1.f, 1.f} - e01;
        f32x2 c2b = f32x2{1.f, 1.f} - e23;

        const float left = shnew, upleft = shprev;
        const float pre0 = fmaf(kup0, c1a.x, -(upleft * c2a.x));
        const float pre1 = fmaf(kup1, c1a.y, -(kup0 * c2a.y));
        const float pre2 = fmaf(kup2, c1b.x, -(kup1 * c2b.x));
        const float pre3 = fmaf(kup3, c1b.y, -(kup2 * c2b.y));
        const float t0 = fmaf(left, c1a.x, pre0);
        const float t1 = fmaf(t0,   c1a.y, pre1);
        const float t2 = fmaf(t1,   c1b.x, pre2);
        const float t3 = fmaf(t2,   c1b.y, pre3);
        shprev = shnew;
        kup0 = t0; kup1 = t1; kup2 = t2; kup3 = t3;
        shnew = wave_shr1(t3, 1.0f);
    };

    // 6-deep prefetch, 6-step unrolled body; 318 = 6*52 + 6 (last 6 no-reload)
    uint2 b0 = LOADK(0), b1 = LOADK(1), b2 = LOADK(2),
          b3 = LOADK(3), b4 = LOADK(4), b5 = LOADK(5);
    gp += 6 * 256;
    for (int it = 0; it < 52; ++it) {
        STEP(b0); b0 = LOADK(0);
        STEP(b1); b1 = LOADK(1);
        STEP(b2); b2 = LOADK(2);
        STEP(b3); b3 = LOADK(3);
        STEP(b4); b4 = LOADK(4);
        STEP(b5); b5 = LOADK(5);
        gp += 6 * 256;
    }
    STEP(b0); STEP(b1); STEP(b2); STEP(b3); STEP(b4); STEP(b5);

    if (lane == 63) atomicAdd(out, w * kup2);
}

// ---------------- fallback (R4, passes, no workspace) ----------------
__global__ __launch_bounds__(64)
void sig_pde(const float* __restrict__ X, const float* __restrict__ Y,
             float* __restrict__ out) {
    const int pid  = blockIdx.x;
    const int pair = pid >> 7;
    const int a    = pid & 127;
    const float* U = (pair == 1) ? Y : X;
    const float* V = (pair == 0) ? X : Y;
    const float  w = (pair == 2) ? (-2.0f / (float)NA) : (1.0f / (float)NA);
    U += (size_t)a * (NPTS * DD);
    V += (size_t)a * (NPTS * DD);
    __shared__ float dU[4][256][4];
    const int lane = threadIdx.x;
    const float4* U4 = (const float4*)U;
    #pragma unroll
    for (int i = 0; i < 16; ++i) {
        int t = lane + (i << 6);
        int qd = t >> 8, r = t & 255;
        float4 val = make_float4(0.f, 0.f, 0.f, 0.f);
        if (r < MMI) {
            float4 lo = U4[r * 4 + qd], hi = U4[r * 4 + 4 + qd];
            val = make_float4(hi.x - lo.x, hi.y - lo.y, hi.z - lo.z, hi.w - lo.w);
        }
        *(float4*)(&dU[qd][r][0]) = val;
    }
    f32x2 v[4][8];
    #pragma unroll
    for (int k = 0; k < 4; ++k) {
        int j = (lane << 2) + k;
        const bool valid = (j < MMI);
        const int jj = valid ? j : 0;
        const float2* Va = (const float2*)(V + (size_t)jj * DD);
        const float2* Vb = (const float2*)(V + (size_t)(jj + 1) * DD);
        #pragma unroll
        for (int q = 0; q < 8; ++q) {
            float2 lo = Va[q], hi = Vb[q];
            v[k][q] = valid ? f32x2{hi.x - lo.x, hi.y - lo.y} : f32x2{0.f, 0.f};
        }
    }
    __syncthreads();
    auto rowidx = [&](int s) {
        int rr = s - lane;
        return ((unsigned)rr < (unsigned)MMI) ? rr : 255;
    };
    auto load_row = [&](int s, f32x2* uu) {
        const float4* p = (const float4*)&dU[0][rowidx(s)][0];
        #pragma unroll
        for (int q = 0; q < 4; ++q) {
            float4 t = p[q << 8];
            uu[2 * q + 0] = f32x2{t.x, t.y};
            uu[2 * q + 1] = f32x2{t.z, t.w};
        }
    };
    float c1[4], c2[4];
    auto compute_c = [&](const f32x2* uu) {
        #pragma unroll
        for (int k = 0; k < 4; ++k) {
            f32x2 acc = uu[0] * v[k][0];
            #pragma unroll
            for (int q = 1; q < 8; ++q) acc += uu[q] * v[k][q];
            const float g = acc.x + acc.y;
            const float e = g * g * (1.0f / 12.0f);
            c1[k] = fmaf(0.5f, g, 1.0f) + e;
            c2[k] = 1.0f - e;
        }
    };
    float kup0 = 1.f, kup1 = 1.f, kup2 = 1.f, kup3 = 1.f;
    float shnew = 1.f, shprev = 1.f;
    auto step = [&]() {
        const float left = shnew, upleft = shprev;
        const float pre0 = fmaf(kup0, c1[0], -(upleft * c2[0]));
        const float pre1 = fmaf(kup1, c1[1], -(kup0 * c2[1]));
        const float pre2 = fmaf(kup2, c1[2], -(kup1 * c2[2]));
        const float pre3 = fmaf(kup3, c1[3], -(kup2 * c2[3]));
        const float t0 = fmaf(left, c1[0], pre0);
        const float t1 = fmaf(t0,   c1[1], pre1);
        const float t2 = fmaf(t1,   c1[2], pre2);
        const float t3 = fmaf(t2,   c1[3], pre3);
        shprev = shnew;
        kup0 = t0; kup1 = t1; kup2 = t2; kup3 = t3;
        shnew = wave_shr1(t3, 1.0f);
    };
    f32x2 bufA[8], bufB[8], bufC[8];
    {
        f32x2 t[8];
        load_row(0, t);
        compute_c(t);
    }
    load_row(1, bufA);
    load_row(2, bufB);
    for (int s = 0; s < NSTEP; s += 3) {
        load_row(s + 3, bufC); step(); compute_c(bufA);
        load_row(s + 4, bufA); step(); compute_c(bufB);
        load_row(s + 5, bufB); step(); compute_c(bufC);
    }
    if (lane == 63) atomicAdd(out, w * kup2);
}

extern "C" void kernel_launch(void* const* d_in, const int* in_sizes, int n_in,
                              void* d_out, int out_size, void* d_ws, size_t ws_size,
                              hipStream_t stream) {
    const float* X = (const float*)d_in[0];
    const float* Y = (const float*)d_in[1];
    float* out = (float*)d_out;
    hipMemsetAsync(out, 0, sizeof(float), stream);
    if (ws_size >= G_BYTES) {
        __half* G = (__half*)d_ws;
        sig_gram<<<dim3(3 * NA * 4), dim3(256), 0, stream>>>(X, Y, G);
        sig_pde2<<<dim3(3 * NA), dim3(64), 0, stream>>>(G, out);
    } else {
        sig_pde<<<dim3(3 * NA), dim3(64), 0, stream>>>(X, Y, out);
    }
}